// Round 14
// baseline (184.476 us; speedup 1.0000x reference)
//
#include <hip/hip_runtime.h>

#define N_NODES 50000
#define N_EDGES 800000
#define DIM 128
#define NT 4
#define NR 6
#define NH 8
#define NBLK_SCAN ((N_NODES + 255) / 256)   // 196 (type-hist blocks)
#define NBLK2 ((N_NODES + 1023) / 1024)     // 49  (edge-count scan blocks)
#define NTILE_ROW 3129                      // ceil((N + 4*15)/16)
#define NPAD_MAX (NTILE_ROW * 16)           // 50064

#define XCVT_N (N_NODES * DIM / 4)          // 1,600,000 float4s
#define WT_N   (NT * 3 * DIM * DIM)         // 196,608 elems
#define WCB_N  (24 * 32)                    // 768 uint4 entries
#define PREP_TOTAL (XCVT_N + WT_N + WCB_N)
#define PREP_BLOCKS ((PREP_TOTAL + 255) / 256)
#define HIST_BLOCKS (N_EDGES / 256)                     // 3125
#define A_PREP_BASE NBLK_SCAN
#define A_HIST_BASE (NBLK_SCAN + PREP_BLOCKS)
#define A_BLOCKS (A_HIST_BASE + HIST_BLOCKS)

// k_D grid: roles interleaved. b%3==2 -> emit chunk b/3 (512 edges, 2/thread);
// else projm tile 2*(b/3)+(b%3). Tiles 0..3128 need b up to 4692.
// NOTE: grid also produces phantom emit chunk 1563 (b=4691) — guarded OOB in-kernel.
#define D_BLOCKS 4693

typedef __attribute__((ext_vector_type(8))) short bf16x8;
typedef __attribute__((ext_vector_type(4))) float f32x4;

__device__ __forceinline__ unsigned short f2bf(float f) {
    unsigned int u = __float_as_uint(f);
    return (unsigned short)((u + 0x7fffu + ((u >> 16) & 1u)) >> 16);
}
__device__ __forceinline__ float blo(unsigned int u) { return __uint_as_float(u << 16); }
__device__ __forceinline__ float bhi(unsigned int u) { return __uint_as_float(u & 0xffff0000u); }

__device__ __forceinline__ int sign_index(int s) {
    // es = where((s < -1)|(s==0), -2, clip(s,-1,1)); idx: -1->0, 1->1, else->2
    if (s < -1 || s == 0) return 2;
    return (s == -1) ? 0 : 1;
}

// ============ A: typehist | prep | hist2 (all mutually independent) ============
__global__ __launch_bounds__(256) void k_A(
    const int* __restrict__ ntype, int* __restrict__ bhist, int* __restrict__ opad,
    const float* __restrict__ x,
    const float* __restrict__ Wq, const float* __restrict__ Wk, const float* __restrict__ Wv,
    const float* __restrict__ rel_q, const float* __restrict__ rel_k,
    const float* __restrict__ rel_v,
    const float* __restrict__ skn, const float* __restrict__ svn,
    unsigned short* __restrict__ xb, unsigned short* __restrict__ Wt,
    uint4* __restrict__ wcb,
    const int* __restrict__ ei, int* __restrict__ cnt, int* __restrict__ posw)
{
    int blk = blockIdx.x;
    if (blk < NBLK_SCAN) {
        // ---- node-type histogram + opad init ----
        __shared__ int h[NT];
        if (threadIdx.x < NT) h[threadIdx.x] = 0;
        __syncthreads();
        int n = blk * 256 + threadIdx.x;
        if (n < N_NODES) atomicAdd(&h[ntype[n]], 1);
        if (n < NPAD_MAX) opad[n] = -1;
        __syncthreads();
        if (threadIdx.x < NT) bhist[blk * NT + threadIdx.x] = h[threadIdx.x];
        return;
    }
    if (blk < A_HIST_BASE) {
        // ---- prep: x->bf16 | W->bf16 transposed | packed bf16 weight table ----
        int i = (blk - A_PREP_BASE) * 256 + threadIdx.x;
        if (i < XCVT_N) {
            float4 v = ((const float4*)x)[i];
            ushort4 o;
            o.x = f2bf(v.x); o.y = f2bf(v.y); o.z = f2bf(v.z); o.w = f2bf(v.w);
            ((ushort4*)xb)[i] = o;
        } else if (i < XCVT_N + WT_N) {
            int j = i - XCVT_N;            // Wt[ts][out][in], ts = t*3+sel
            int in = j & 127;
            int b2 = j >> 7;
            int out = b2 & 127;
            int ts = b2 >> 7;
            int sel = ts % 3, t = ts / 3;
            const float* W = sel == 0 ? Wq : (sel == 1 ? Wk : Wv);
            Wt[j] = f2bf(W[((size_t)t * DIM + in) * DIM + out]);
        } else if (i < PREP_TOTAL) {
            // wcb[cmb][p]: dword q = {wk(4p+q) | wv(4p+q)<<16}  (matches KV {k|v<<16})
            int j = i - XCVT_N - WT_N;     // cmb*32 + p
            int p = j & 31;
            int cmb = j >> 5;
            int et = cmb & 7, sidx = cmb >> 3;
            if (et < NR) {
                int h2 = p >> 2;
                unsigned d[4];
                #pragma unroll
                for (int q = 0; q < 4; ++q) {
                    int o = 4 * p + q;
                    int rb = (et * NH + h2) * 16 + (o & 15);
                    float sgk = sidx == 0 ? -1.f : (sidx == 1 ? 1.f : skn[o]);
                    float sgv = sidx == 0 ? -1.f : (sidx == 1 ? 1.f : svn[o]);
                    float wk = rel_q[rb] * rel_k[rb] * sgk * 0.25f;
                    float wv = rel_v[rb] * sgv;
                    d[q] = (unsigned)f2bf(wk) | ((unsigned)f2bf(wv) << 16);
                }
                uint4 u; u.x = d[0]; u.y = d[1]; u.z = d[2]; u.w = d[3];
                wcb[cmb * 32 + p] = u;
            }
        }
        return;
    }
    // ---- edge histogram with position-within return (cnt pre-zeroed by memset) ----
    int e = (blk - A_HIST_BASE) * 256 + threadIdx.x;
    if (e < N_EDGES) posw[e] = atomicAdd(&cnt[ei[N_EDGES + e]], 1);
}

// ============ B: typescan (block 0) | scan1 (blocks 1..NBLK2) ============
__global__ __launch_bounds__(1024) void k_B(
    const int* __restrict__ bhist, int* __restrict__ bbase, int* __restrict__ pb_g,
    const int* __restrict__ cnt, int* __restrict__ offs, int* __restrict__ bsum)
{
    int tid = threadIdx.x;
    if (blockIdx.x == 0) {
        // ---- scan block histograms (type-major) -> per-(block,type) bases, padded x16 ----
        __shared__ int s[1024];
        __shared__ int pb[NT + 1];
        int t = tid / NBLK_SCAN;
        int b = tid - t * NBLK_SCAN;
        int v = (tid < NT * NBLK_SCAN) ? bhist[b * NT + t] : 0;
        s[tid] = v;
        __syncthreads();
        for (int d = 1; d < 1024; d <<= 1) {
            int add = (tid >= d) ? s[tid - d] : 0;
            __syncthreads();
            s[tid] += add;
            __syncthreads();
        }
        if (tid == 0) {
            int acc = 0;
            for (int tt = 0; tt < NT; ++tt) {
                pb[tt] = acc;
                int tot = s[(tt + 1) * NBLK_SCAN - 1] - (tt ? s[tt * NBLK_SCAN - 1] : 0);
                acc += ((tot + 15) >> 4) << 4;
            }
            pb[NT] = acc;
        }
        __syncthreads();
        if (tid < NT * NBLK_SCAN) {
            int excl = s[tid] - v;
            int base_t = t ? s[t * NBLK_SCAN - 1] : 0;
            bbase[b * NT + t] = pb[t] + (excl - base_t);
        }
        if (tid <= NT) pb_g[tid] = pb[tid];
        return;
    }
    // ---- scan1: block-local exclusive scan of edge counts (1024 elems/block) ----
    int sb = blockIdx.x - 1;
    __shared__ int s[1024];
    int i = sb * 1024 + tid;
    int v = (i < N_NODES) ? cnt[i] : 0;
    s[tid] = v;
    __syncthreads();
    for (int d = 1; d < 1024; d <<= 1) {
        int add = (tid >= d) ? s[tid - d] : 0;
        __syncthreads();
        s[tid] += add;
        __syncthreads();
    }
    if (i < N_NODES) offs[i] = s[tid] - v;
    if (tid == 1023) bsum[sb] = s[1023];
}

// ============ C: scatter+slot (blocks 0..195) | scan2 (block 196) ============
__global__ __launch_bounds__(256) void k_C(
    const int* __restrict__ ntype, const int* __restrict__ bbase, int* __restrict__ order_pad,
    int* __restrict__ slot,
    const int* __restrict__ bsum, int* __restrict__ bofs, int* __restrict__ offs)
{
    int blk = blockIdx.x;
    if (blk < NBLK_SCAN) {
        __shared__ int cur[NT];
        if (threadIdx.x < NT) cur[threadIdx.x] = bbase[blk * NT + threadIdx.x];
        __syncthreads();
        int n = blk * 256 + threadIdx.x;
        if (n < N_NODES) {
            int t = ntype[n];
            int pos = atomicAdd(&cur[t], 1);   // LDS atomic
            order_pad[pos] = n;
            slot[n] = pos;
        }
        return;
    }
    // ---- scan2 over NBLK2 block sums; offs[N] pre-compensated for bofs ----
    __shared__ int s[256];
    int t = threadIdx.x;
    int v = (t < NBLK2) ? bsum[t] : 0;
    s[t] = v;
    __syncthreads();
    for (int d = 1; d < 256; d <<= 1) {
        int add = (t >= d) ? s[t - d] : 0;
        __syncthreads();
        s[t] += add;
        __syncthreads();
    }
    if (t < NBLK2) {
        int b = s[t] - v;
        bofs[t] = b;
        if (t == NBLK2 - 1) offs[N_NODES] = N_EDGES - b;  // so offs[N]+bofs[N>>10]==E
    }
}

// ============ D: projm tiles and emit chunks, INTERLEAVED by blockIdx ============
// b%3==2 -> emit chunk b/3 (512 edges, 2 per thread, independent chains);
// else   -> projm tile 2*(b/3)+(b%3).
// Latency-bound emit waves co-reside with MFMA-heavy projm waves on every CU.
__global__ __launch_bounds__(256) void k_D(
    const unsigned short* __restrict__ xb, const unsigned short* __restrict__ Wt,
    const int* __restrict__ order_pad, const int* __restrict__ pb_g,
    const float* __restrict__ bq, const float* __restrict__ bk, const float* __restrict__ bv,
    float* __restrict__ Qf, unsigned int* __restrict__ KVu,
    const int* __restrict__ slot,
    const int* __restrict__ ei, const int* __restrict__ etype,
    const int* __restrict__ esign, const float* __restrict__ edist,
    const float* __restrict__ dalpha, const float* __restrict__ dtau,
    const int* __restrict__ offs, const int* __restrict__ bofs,
    const int* __restrict__ posw, int2* __restrict__ edata)
{
    int b = blockIdx.x;
    int d3 = b / 3, m = b - d3 * 3;
    if (m == 2) {
        // ---- emit: 2 edges/thread, both dependency chains issued up front ----
        int e0 = d3 * 512 + threadIdx.x;
        if (e0 >= N_EDGES) return;           // phantom chunk (d3=1563) guard — r13 crash fix
        int e1 = e0 + 256;
        bool v1 = (e1 < N_EDGES);
        int dst0 = ei[N_EDGES + e0];
        int src0 = ei[e0];
        int dst1 = v1 ? ei[N_EDGES + e1] : 0;
        int src1 = v1 ? ei[e1] : 0;
        int pw0 = posw[e0];
        int pw1 = v1 ? posw[e1] : 0;
        int sl0 = slot[src0];                // random gather (chain 0)
        int sl1 = slot[src1];                // random gather (chain 1)
        int of0 = offs[dst0] + bofs[dst0 >> 10];   // random gather (chain 0)
        int of1 = offs[dst1] + bofs[dst1 >> 10];   // random gather (chain 1)
        int cmb0 = sign_index(esign[e0]) * 8 + etype[e0];
        int cmb1 = v1 ? (sign_index(esign[e1]) * 8 + etype[e1]) : 0;
        float rtau = 1.f / (dtau[0] + 1e-9f);
        float da = dalpha[0];
        float phi0 = da * __expf(-edist[e0] * rtau);
        float phi1 = da * __expf(-(v1 ? edist[e1] : 0.f) * rtau);
        edata[of0 + pw0] = make_int2(sl0 | (cmb0 << 16), __float_as_int(phi0));
        if (v1) edata[of1 + pw1] = make_int2(sl1 | (cmb1 << 16), __float_as_int(phi1));
        return;
    }
    int tile = d3 * 2 + m;
    if (tile >= NTILE_ROW) return;
    int row0 = tile * 16;
    if (row0 >= pb_g[NT]) return;
    // tile is fully within one type's padded (x16) region
    int t = (row0 >= pb_g[3]) ? 3 : (row0 >= pb_g[2]) ? 2 : (row0 >= pb_g[1]) ? 1 : 0;
    int wave = threadIdx.x >> 6, lane = threadIdx.x & 63;
    int col = wave * 16 + (lane & 15);     // 0..63
    int arow = row0 + (lane & 15);
    int nidA = order_pad[arow];
    const unsigned short* xrow = xb + (size_t)(nidA < 0 ? 0 : nidA) * DIM;
    int ko = (lane >> 4) * 8;
    bf16x8 afrag[4];
    #pragma unroll
    for (int kt = 0; kt < 4; ++kt) afrag[kt] = *(const bf16x8*)(xrow + kt * 32 + ko);

    // Q phase: 2 column groups, direct stores to contiguous slot rows
    #pragma unroll
    for (int g = 0; g < 2; ++g) {
        int wcol = g * 64 + col;
        const unsigned short* wrow = Wt + ((size_t)(t * 3 + 0) * DIM + wcol) * DIM;
        f32x4 acc = {0.f, 0.f, 0.f, 0.f};
        #pragma unroll
        for (int kt = 0; kt < 4; ++kt) {
            bf16x8 bfr = *(const bf16x8*)(wrow + kt * 32 + ko);
            acc = __builtin_amdgcn_mfma_f32_16x16x32_bf16(afrag[kt], bfr, acc, 0, 0, 0);
        }
        float bias = bq[t * DIM + wcol];
        #pragma unroll
        for (int r = 0; r < 4; ++r) {
            int lrow = (lane >> 4) * 4 + r;
            Qf[(size_t)(row0 + lrow) * DIM + wcol] = acc[r] + bias;
        }
    }
    // KV phase: 2 column groups; K and V for the same column -> one packed dword
    #pragma unroll
    for (int g = 0; g < 2; ++g) {
        int wcol = g * 64 + col;
        const unsigned short* wrowK = Wt + ((size_t)(t * 3 + 1) * DIM + wcol) * DIM;
        const unsigned short* wrowV = Wt + ((size_t)(t * 3 + 2) * DIM + wcol) * DIM;
        f32x4 accK = {0.f, 0.f, 0.f, 0.f};
        f32x4 accV = {0.f, 0.f, 0.f, 0.f};
        #pragma unroll
        for (int kt = 0; kt < 4; ++kt) {
            bf16x8 bK = *(const bf16x8*)(wrowK + kt * 32 + ko);
            bf16x8 bV = *(const bf16x8*)(wrowV + kt * 32 + ko);
            accK = __builtin_amdgcn_mfma_f32_16x16x32_bf16(afrag[kt], bK, accK, 0, 0, 0);
            accV = __builtin_amdgcn_mfma_f32_16x16x32_bf16(afrag[kt], bV, accV, 0, 0, 0);
        }
        float bk_ = bk[t * DIM + wcol], bv_ = bv[t * DIM + wcol];
        #pragma unroll
        for (int r = 0; r < 4; ++r) {
            int lrow = (lane >> 4) * 4 + r;
            unsigned d = (unsigned)f2bf(accK[r] + bk_) | ((unsigned)f2bf(accV[r] + bv_) << 16);
            KVu[(size_t)(row0 + lrow) * DIM + wcol] = d;
        }
    }
}

// ============ E: fused attention + aggregation + skip + LN ============
// 256 threads = 4 waves; one wave per node. Each 32-lane HALF owns one edge;
// lane holds a 4-element quad. Score reduce = 2 width-4 shuffles.
__global__ __launch_bounds__(256) void k_attn(
    const float4* __restrict__ Qf4, const uint4* __restrict__ KV,
    const uint4* __restrict__ WCB,
    const float* __restrict__ x, const int* __restrict__ ntype,
    const int* __restrict__ slot,
    const int* __restrict__ offs, const int* __restrict__ bofs,
    const int2* __restrict__ edata,
    const float* __restrict__ rbias, const float* __restrict__ skip,
    const float* __restrict__ gmm, const float* __restrict__ bta,
    float* __restrict__ out)
{
    __shared__ float rb_s[NR * NH];
    if (threadIdx.x < NR * NH) rb_s[threadIdx.x] = rbias[threadIdx.x];
    __syncthreads();
    const int wave = threadIdx.x >> 6, lane = threadIdx.x & 63;
    const int n = blockIdx.x * 4 + wave;
    const int p = lane & 31;          // position quad index (elems 4p..4p+3)
    const int hi = lane >> 5;         // which edge of the pair this half owns
    const int h = p >> 2;             // head
    const int beg = offs[n] + bofs[n >> 10];
    const int end = offs[n + 1] + bofs[(n + 1) >> 10];

    const int sl = slot[n];           // own Q row in slot space (wave-uniform broadcast)
    const float4 q4 = Qf4[(size_t)sl * 32 + p];

    float Z = 0.f, a0 = 0.f, a1 = 0.f, a2 = 0.f, a3 = 0.f;

    // scores bounded; exp without max-shift is safe in f32 (softmax shift-invariant)
    // kv dword e = {k|v<<16}; wcb dword e = {wk|wv<<16}
    auto process = [&](int2 r) {
        int src = r.x & 0xffff;       // slot-space KV row
        unsigned cmb = ((unsigned)r.x) >> 16;
        uint4 kv = KV[(size_t)src * 32 + p];
        uint4 w = WCB[cmb * 32 + p];
        float pp = (q4.x * blo(w.x)) * blo(kv.x);
        pp = fmaf(q4.y * blo(w.y), blo(kv.y), pp);
        pp = fmaf(q4.z * blo(w.z), blo(kv.z), pp);
        pp = fmaf(q4.w * blo(w.w), blo(kv.w), pp);
        pp += __shfl_xor(pp, 1, 4);
        pp += __shfl_xor(pp, 2, 4);
        float ex = __expf(pp + rb_s[(cmb & 7) * NH + h] + __int_as_float(r.y));
        Z += ex;
        a0 = fmaf(bhi(kv.x) * bhi(w.x), ex, a0);
        a1 = fmaf(bhi(kv.y) * bhi(w.y), ex, a1);
        a2 = fmaf(bhi(kv.z) * bhi(w.z), ex, a2);
        a3 = fmaf(bhi(kv.w) * bhi(w.w), ex, a3);
    };

    int rem = end - beg;
    int j = beg;
    if (rem >= 4) {
        // 2-pair (4-edge) unroll with 1-iter-ahead edata prefetch
        int2 r0 = edata[j + hi];
        int2 r1 = edata[j + 2 + hi];
        while (true) {
            int2 c0 = r0, c1 = r1;
            j += 4; rem -= 4;
            if (rem >= 4) { r0 = edata[j + hi]; r1 = edata[j + 2 + hi]; }
            process(c0);
            process(c1);
            if (rem < 4) break;
        }
    }
    while (rem >= 2) {
        int2 c = edata[j + hi];
        process(c);
        j += 2; rem -= 2;
    }
    if (rem) {
        // single leftover edge: both halves compute it; gate the hi half to zero
        int2 r = edata[j];
        int src = r.x & 0xffff;
        unsigned cmb = ((unsigned)r.x) >> 16;
        uint4 kv = KV[(size_t)src * 32 + p];
        uint4 w = WCB[cmb * 32 + p];
        float pp = (q4.x * blo(w.x)) * blo(kv.x);
        pp = fmaf(q4.y * blo(w.y), blo(kv.y), pp);
        pp = fmaf(q4.z * blo(w.z), blo(kv.z), pp);
        pp = fmaf(q4.w * blo(w.w), blo(kv.w), pp);
        pp += __shfl_xor(pp, 1, 4);
        pp += __shfl_xor(pp, 2, 4);
        float ex = __expf(pp + rb_s[(cmb & 7) * NH + h] + __int_as_float(r.y));
        ex = hi ? 0.f : ex;
        Z += ex;
        a0 = fmaf(bhi(kv.x) * bhi(w.x), ex, a0);
        a1 = fmaf(bhi(kv.y) * bhi(w.y), ex, a1);
        a2 = fmaf(bhi(kv.z) * bhi(w.z), ex, a2);
        a3 = fmaf(bhi(kv.w) * bhi(w.w), ex, a3);
    }

    // merge the two halves (lanes l and l+32 hold the same positions)
    Z  += __shfl_xor(Z, 32, 64);
    a0 += __shfl_xor(a0, 32, 64);
    a1 += __shfl_xor(a1, 32, 64);
    a2 += __shfl_xor(a2, 32, 64);
    a3 += __shfl_xor(a3, 32, 64);

    float rz = 1.f / (Z + 1e-9f);
    int t = ntype[n];
    float alpha = 1.f / (1.f + __expf(-skip[t]));
    float4 x4 = ((const float4*)x)[(size_t)n * 32 + p];
    float m0 = fmaf(alpha, a0 * rz - x4.x, x4.x);
    float m1 = fmaf(alpha, a1 * rz - x4.y, x4.y);
    float m2 = fmaf(alpha, a2 * rz - x4.z, x4.z);
    float m3 = fmaf(alpha, a3 * rz - x4.w, x4.w);

    float s = (m0 + m1) + (m2 + m3);
    float s2 = fmaf(m0, m0, m1 * m1) + fmaf(m2, m2, m3 * m3);
    #pragma unroll
    for (int d = 32; d >= 1; d >>= 1) {
        s += __shfl_xor(s, d, 64);
        s2 += __shfl_xor(s2, d, 64);
    }
    // both halves duplicated -> divide by 2*DIM
    float mu = s * (1.f / (2 * DIM));
    float var = s2 * (1.f / (2 * DIM)) - mu * mu;
    float rstd = rsqrtf(var + 1e-5f);
    if (hi == 0) {
        float4 g4 = ((const float4*)gmm)[t * 32 + p];
        float4 b4 = ((const float4*)bta)[t * 32 + p];
        float4 o4;
        o4.x = (m0 - mu) * rstd * g4.x + b4.x;
        o4.y = (m1 - mu) * rstd * g4.y + b4.y;
        o4.z = (m2 - mu) * rstd * g4.z + b4.z;
        o4.w = (m3 - mu) * rstd * g4.w + b4.w;
        ((float4*)out)[(size_t)n * 32 + p] = o4;
    }
}

extern "C" void kernel_launch(void* const* d_in, const int* in_sizes, int n_in,
                              void* d_out, int out_size, void* d_ws, size_t ws_size,
                              hipStream_t stream) {
    const float* x      = (const float*)d_in[0];
    const int*   ntype  = (const int*)d_in[1];
    const int*   ei     = (const int*)d_in[2];
    const int*   etype  = (const int*)d_in[3];
    const int*   esign  = (const int*)d_in[4];
    const float* edist  = (const float*)d_in[5];
    const float* Wq     = (const float*)d_in[6];
    const float* bq     = (const float*)d_in[7];
    const float* Wk     = (const float*)d_in[8];
    const float* bk     = (const float*)d_in[9];
    const float* Wv     = (const float*)d_in[10];
    const float* bv     = (const float*)d_in[11];
    const float* rel_q  = (const float*)d_in[12];
    const float* rel_k  = (const float*)d_in[13];
    const float* rel_v  = (const float*)d_in[14];
    const float* skn    = (const float*)d_in[15];
    const float* svn    = (const float*)d_in[16];
    const float* rbias  = (const float*)d_in[17];
    const float* dalpha = (const float*)d_in[18];
    const float* dtau   = (const float*)d_in[19];
    const float* skip   = (const float*)d_in[20];
    const float* gmm    = (const float*)d_in[21];
    const float* bta    = (const float*)d_in[22];
    float* out = (float*)d_out;

    // All offsets are multiples of 512 B (row-aligned — KV/Q rows must not straddle
    // extra cache lines; the r10/r11 regression was a 160 B-misaligned KVu base).
    char* ws = (char*)d_ws;
    float*          Qf     = (float*)         (ws + 0);          // NPAD*512B (slot order)
    unsigned int*   KVu    = (unsigned int*)  (ws + 25632768);   // NPAD*512B (slot order, {k|v<<16})
    unsigned short* xb     = (unsigned short*)(ws + 51265536);   // 12.8 MB
    unsigned short* Wt     = (unsigned short*)(ws + 64065536);   // 393 KB
    uint4*          wcb    = (uint4*)         (ws + 64458752);   // 12.3 KB
    int*            cnt    = (int*)           (ws + 64471040);   // N
    int*            offs   = (int*)           (ws + 64672256);   // N+1
    int*            bsum   = (int*)           (ws + 64873472);   // 64
    int*            bofs   = (int*)           (ws + 64873984);   // 64
    int*            posw   = (int*)           (ws + 64874496);   // E = 3.2 MB
    int2*           edata  = (int2*)          (ws + 68074496);   // E*8 = 6.4 MB
    int*            opad   = (int*)           (ws + 74475008);   // NPAD_MAX
    int*            slot   = (int*)           (ws + 74675712);   // N
    int*            bhist  = (int*)           (ws + 74876416);   // 196*4
    int*            bbase  = (int*)           (ws + 74880512);   // 196*4
    int*            pb     = (int*)           (ws + 74884608);   // 5

    // 0. zero edge counters (must precede A's hist2 role)
    hipMemsetAsync(cnt, 0, (size_t)N_NODES * 4, stream);
    // A. typehist | prep | edge-histogram  (mutually independent)
    k_A <<<A_BLOCKS, 256, 0, stream>>>(ntype, bhist, opad,
                                       x, Wq, Wk, Wv, rel_q, rel_k, rel_v, skn, svn,
                                       xb, Wt, wcb, ei, cnt, posw);
    // B. typescan | scan1
    k_B <<<1 + NBLK2, 1024, 0, stream>>>(bhist, bbase, pb, cnt, offs, bsum);
    // C. scatter+slot | scan2
    k_C <<<NBLK_SCAN + 1, 256, 0, stream>>>(ntype, bbase, opad, slot, bsum, bofs, offs);
    // D. projm | emit, roles interleaved per blockIdx (emit latency hides under MFMA)
    k_D <<<D_BLOCKS, 256, 0, stream>>>(xb, Wt, opad, pb, bq, bk, bv,
                                       Qf, KVu, slot,
                                       ei, etype, esign, edist, dalpha, dtau,
                                       offs, bofs, posw, edata);
    // E. fused attention + aggregation + skip + LayerNorm
    k_attn <<<N_NODES / 4, 256, 0, stream>>>((const float4*)Qf, (const uint4*)KVu,
                                             (const uint4*)wcb, x, ntype, slot, offs, bofs,
                                             edata, rbias, skip, gmm, bta, out);
}

// Round 15
// 180.866 us; speedup vs baseline: 1.0200x; 1.0200x over previous
//
#include <hip/hip_runtime.h>

#define N_NODES 50000
#define N_EDGES 800000
#define DIM 128
#define NT 4
#define NR 6
#define NH 8
#define NBLK_SCAN ((N_NODES + 255) / 256)   // 196 (type-hist blocks)
#define NBLK2 ((N_NODES + 1023) / 1024)     // 49  (edge-count scan blocks)
#define NTILE_ROW 3129                      // ceil((N + 4*15)/16)
#define NPAD_MAX (NTILE_ROW * 16)           // 50064

#define XCVT_N (N_NODES * DIM / 4)          // 1,600,000 float4s
#define WT_N   (NT * 3 * DIM * DIM)         // 196,608 elems
#define WCB_N  (24 * 32)                    // 768 uint4 entries
#define PREP_TOTAL (XCVT_N + WT_N + WCB_N)
#define PREP_BLOCKS ((PREP_TOTAL + 255) / 256)
#define HIST_BLOCKS (N_EDGES / 256)                     // 3125
#define A_PREP_BASE NBLK_SCAN
#define A_HIST_BASE (NBLK_SCAN + PREP_BLOCKS)
#define A_BLOCKS (A_HIST_BASE + HIST_BLOCKS)

#define PCHUNK 4
#define PROJ_BLOCKS ((NTILE_ROW + PCHUNK - 1) / PCHUNK)   // 783
#define EMIT_BLOCKS ((N_EDGES + 511) / 512)               // 1563 (2 edges/thread)

typedef __attribute__((ext_vector_type(8))) short bf16x8;
typedef __attribute__((ext_vector_type(4))) float f32x4;

__device__ __forceinline__ unsigned short f2bf(float f) {
    unsigned int u = __float_as_uint(f);
    return (unsigned short)((u + 0x7fffu + ((u >> 16) & 1u)) >> 16);
}
__device__ __forceinline__ float blo(unsigned int u) { return __uint_as_float(u << 16); }
__device__ __forceinline__ float bhi(unsigned int u) { return __uint_as_float(u & 0xffff0000u); }

__device__ __forceinline__ int sign_index(int s) {
    // es = where((s < -1)|(s==0), -2, clip(s,-1,1)); idx: -1->0, 1->1, else->2
    if (s < -1 || s == 0) return 2;
    return (s == -1) ? 0 : 1;
}

// ============ A: typehist | prep | hist2 (all mutually independent) ============
__global__ __launch_bounds__(256) void k_A(
    const int* __restrict__ ntype, int* __restrict__ bhist, int* __restrict__ opad,
    const float* __restrict__ x,
    const float* __restrict__ Wq, const float* __restrict__ Wk, const float* __restrict__ Wv,
    const float* __restrict__ rel_q, const float* __restrict__ rel_k,
    const float* __restrict__ rel_v,
    const float* __restrict__ skn, const float* __restrict__ svn,
    unsigned short* __restrict__ xb, unsigned short* __restrict__ Wt,
    uint4* __restrict__ wcb,
    const int* __restrict__ ei, int* __restrict__ cnt, int* __restrict__ posw)
{
    int blk = blockIdx.x;
    if (blk < NBLK_SCAN) {
        // ---- node-type histogram + opad init ----
        __shared__ int h[NT];
        if (threadIdx.x < NT) h[threadIdx.x] = 0;
        __syncthreads();
        int n = blk * 256 + threadIdx.x;
        if (n < N_NODES) atomicAdd(&h[ntype[n]], 1);
        if (n < NPAD_MAX) opad[n] = -1;
        __syncthreads();
        if (threadIdx.x < NT) bhist[blk * NT + threadIdx.x] = h[threadIdx.x];
        return;
    }
    if (blk < A_HIST_BASE) {
        // ---- prep: x->bf16 | W->bf16 transposed | packed bf16 weight table ----
        int i = (blk - A_PREP_BASE) * 256 + threadIdx.x;
        if (i < XCVT_N) {
            float4 v = ((const float4*)x)[i];
            ushort4 o;
            o.x = f2bf(v.x); o.y = f2bf(v.y); o.z = f2bf(v.z); o.w = f2bf(v.w);
            ((ushort4*)xb)[i] = o;
        } else if (i < XCVT_N + WT_N) {
            int j = i - XCVT_N;            // Wt[ts][out][in], ts = t*3+sel
            int in = j & 127;
            int b2 = j >> 7;
            int out = b2 & 127;
            int ts = b2 >> 7;
            int sel = ts % 3, t = ts / 3;
            const float* W = sel == 0 ? Wq : (sel == 1 ? Wk : Wv);
            Wt[j] = f2bf(W[((size_t)t * DIM + in) * DIM + out]);
        } else if (i < PREP_TOTAL) {
            // wcb[cmb][p]: dword q = {wk(4p+q) | wv(4p+q)<<16}  (matches KV {k|v<<16})
            int j = i - XCVT_N - WT_N;     // cmb*32 + p
            int p = j & 31;
            int cmb = j >> 5;
            int et = cmb & 7, sidx = cmb >> 3;
            if (et < NR) {
                int h2 = p >> 2;
                unsigned d[4];
                #pragma unroll
                for (int q = 0; q < 4; ++q) {
                    int o = 4 * p + q;
                    int rb = (et * NH + h2) * 16 + (o & 15);
                    float sgk = sidx == 0 ? -1.f : (sidx == 1 ? 1.f : skn[o]);
                    float sgv = sidx == 0 ? -1.f : (sidx == 1 ? 1.f : svn[o]);
                    float wk = rel_q[rb] * rel_k[rb] * sgk * 0.25f;
                    float wv = rel_v[rb] * sgv;
                    d[q] = (unsigned)f2bf(wk) | ((unsigned)f2bf(wv) << 16);
                }
                uint4 u; u.x = d[0]; u.y = d[1]; u.z = d[2]; u.w = d[3];
                wcb[cmb * 32 + p] = u;
            }
        }
        return;
    }
    // ---- edge histogram with position-within return (cnt pre-zeroed by memset) ----
    int e = (blk - A_HIST_BASE) * 256 + threadIdx.x;
    if (e < N_EDGES) posw[e] = atomicAdd(&cnt[ei[N_EDGES + e]], 1);
}

// ============ B: typescan (block 0) | scan1 (blocks 1..NBLK2) ============
__global__ __launch_bounds__(1024) void k_B(
    const int* __restrict__ bhist, int* __restrict__ bbase, int* __restrict__ pb_g,
    const int* __restrict__ cnt, int* __restrict__ offs, int* __restrict__ bsum)
{
    int tid = threadIdx.x;
    if (blockIdx.x == 0) {
        // ---- scan block histograms (type-major) -> per-(block,type) bases, padded x16 ----
        __shared__ int s[1024];
        __shared__ int pb[NT + 1];
        int t = tid / NBLK_SCAN;
        int b = tid - t * NBLK_SCAN;
        int v = (tid < NT * NBLK_SCAN) ? bhist[b * NT + t] : 0;
        s[tid] = v;
        __syncthreads();
        for (int d = 1; d < 1024; d <<= 1) {
            int add = (tid >= d) ? s[tid - d] : 0;
            __syncthreads();
            s[tid] += add;
            __syncthreads();
        }
        if (tid == 0) {
            int acc = 0;
            for (int tt = 0; tt < NT; ++tt) {
                pb[tt] = acc;
                int tot = s[(tt + 1) * NBLK_SCAN - 1] - (tt ? s[tt * NBLK_SCAN - 1] : 0);
                acc += ((tot + 15) >> 4) << 4;
            }
            pb[NT] = acc;
        }
        __syncthreads();
        if (tid < NT * NBLK_SCAN) {
            int excl = s[tid] - v;
            int base_t = t ? s[t * NBLK_SCAN - 1] : 0;
            bbase[b * NT + t] = pb[t] + (excl - base_t);
        }
        if (tid <= NT) pb_g[tid] = pb[tid];
        return;
    }
    // ---- scan1: block-local exclusive scan of edge counts (1024 elems/block) ----
    int sb = blockIdx.x - 1;
    __shared__ int s[1024];
    int i = sb * 1024 + tid;
    int v = (i < N_NODES) ? cnt[i] : 0;
    s[tid] = v;
    __syncthreads();
    for (int d = 1; d < 1024; d <<= 1) {
        int add = (tid >= d) ? s[tid - d] : 0;
        __syncthreads();
        s[tid] += add;
        __syncthreads();
    }
    if (i < N_NODES) offs[i] = s[tid] - v;
    if (tid == 1023) bsum[sb] = s[1023];
}

// ============ C: scatter+slot (blocks 0..195) | scan2 (block 196) ============
__global__ __launch_bounds__(256) void k_C(
    const int* __restrict__ ntype, const int* __restrict__ bbase, int* __restrict__ order_pad,
    int* __restrict__ slot,
    const int* __restrict__ bsum, int* __restrict__ bofs, int* __restrict__ offs)
{
    int blk = blockIdx.x;
    if (blk < NBLK_SCAN) {
        __shared__ int cur[NT];
        if (threadIdx.x < NT) cur[threadIdx.x] = bbase[blk * NT + threadIdx.x];
        __syncthreads();
        int n = blk * 256 + threadIdx.x;
        if (n < N_NODES) {
            int t = ntype[n];
            int pos = atomicAdd(&cur[t], 1);   // LDS atomic
            order_pad[pos] = n;
            slot[n] = pos;
        }
        return;
    }
    // ---- scan2 over NBLK2 block sums; offs[N] pre-compensated for bofs ----
    __shared__ int s[256];
    int t = threadIdx.x;
    int v = (t < NBLK2) ? bsum[t] : 0;
    s[t] = v;
    __syncthreads();
    for (int d = 1; d < 256; d <<= 1) {
        int add = (t >= d) ? s[t - d] : 0;
        __syncthreads();
        s[t] += add;
        __syncthreads();
    }
    if (t < NBLK2) {
        int b = s[t] - v;
        bofs[t] = b;
        if (t == NBLK2 - 1) offs[N_NODES] = N_EDGES - b;  // so offs[N]+bofs[N>>10]==E
    }
}

// ============ EMIT: dst-sorted edge records, 2 edges/thread, nontemporal stores ============
__global__ __launch_bounds__(256) void k_emit(
    const int* __restrict__ slot,
    const int* __restrict__ ei, const int* __restrict__ etype,
    const int* __restrict__ esign, const float* __restrict__ edist,
    const float* __restrict__ dalpha, const float* __restrict__ dtau,
    const int* __restrict__ offs, const int* __restrict__ bofs,
    const int* __restrict__ posw, int2* __restrict__ edata)
{
    int e0 = blockIdx.x * 512 + threadIdx.x;
    if (e0 >= N_EDGES) return;
    int e1 = e0 + 256;
    bool v1 = (e1 < N_EDGES);
    int dst0 = ei[N_EDGES + e0];
    int src0 = ei[e0];
    int dst1 = v1 ? ei[N_EDGES + e1] : 0;
    int src1 = v1 ? ei[e1] : 0;
    int pw0 = posw[e0];
    int pw1 = v1 ? posw[e1] : 0;
    int sl0 = slot[src0];                      // random gather (chain 0)
    int sl1 = slot[src1];                      // random gather (chain 1)
    int of0 = offs[dst0] + bofs[dst0 >> 10];   // random gather (chain 0)
    int of1 = offs[dst1] + bofs[dst1 >> 10];   // random gather (chain 1)
    int cmb0 = sign_index(esign[e0]) * 8 + etype[e0];
    int cmb1 = v1 ? (sign_index(esign[e1]) * 8 + etype[e1]) : 0;
    float rtau = 1.f / (dtau[0] + 1e-9f);
    float da = dalpha[0];
    float phi0 = da * __expf(-edist[e0] * rtau);
    float phi1 = da * __expf(-(v1 ? edist[e1] : 0.f) * rtau);
    // nontemporal 8B stores: avoid L2 line-ownership churn from random cross-XCD writes
    long long p0 = ((long long)(unsigned)__float_as_int(phi0) << 32)
                 | (unsigned)(sl0 | (cmb0 << 16));
    __builtin_nontemporal_store(p0, (long long*)(edata + of0 + pw0));
    if (v1) {
        long long p1 = ((long long)(unsigned)__float_as_int(phi1) << 32)
                     | (unsigned)(sl1 | (cmb1 << 16));
        __builtin_nontemporal_store(p1, (long long*)(edata + of1 + pw1));
    }
}

// ============ PROJM: MFMA projection, 4 row-tiles/block, A-frags register-resident ============
// Qf/KVu rows in SLOT order (contiguous per tile -> coalesced dword stores).
// KVu row dword e = {k(e) | v(e)<<16}. B-fragments reloaded only on type change.
__global__ __launch_bounds__(256) void k_projm(
    const unsigned short* __restrict__ xb, const unsigned short* __restrict__ Wt,
    const int* __restrict__ order_pad, const int* __restrict__ pb_g,
    const float* __restrict__ bq, const float* __restrict__ bk, const float* __restrict__ bv,
    float* __restrict__ Qf, unsigned int* __restrict__ KVu)
{
    const int chunk = blockIdx.x;
    const int wave = threadIdx.x >> 6, lane = threadIdx.x & 63;
    const int col = wave * 16 + (lane & 15);   // 0..63
    const int ko = (lane >> 4) * 8;
    const int tmax = pb_g[NT];
    const int pb1 = pb_g[1], pb2 = pb_g[2], pb3 = pb_g[3];

    bf16x8 afrag[PCHUNK][4];
    int row0s[PCHUNK];
    bool valid[PCHUNK];
    #pragma unroll
    for (int tt = 0; tt < PCHUNK; ++tt) {
        int tile = chunk * PCHUNK + tt;
        int row0 = tile * 16;
        row0s[tt] = row0;
        bool v = (tile < NTILE_ROW) && (row0 < tmax);
        valid[tt] = v;
        int arow = row0 + (lane & 15);
        int nidA = v ? order_pad[arow] : -1;
        const unsigned short* xrow = xb + (size_t)(nidA < 0 ? 0 : nidA) * DIM;
        #pragma unroll
        for (int kt = 0; kt < 4; ++kt)
            afrag[tt][kt] = *(const bf16x8*)(xrow + kt * 32 + ko);
    }

    // Q phase: 2 column groups; B-frags reused across the 4 tiles (reload on type change)
    #pragma unroll
    for (int g = 0; g < 2; ++g) {
        int wcol = g * 64 + col;
        int cur_t = -1;
        bf16x8 bfr[4];
        float bias = 0.f;
        #pragma unroll
        for (int tt = 0; tt < PCHUNK; ++tt) {
            if (!valid[tt]) continue;
            int row0 = row0s[tt];
            int t = (row0 >= pb3) ? 3 : (row0 >= pb2) ? 2 : (row0 >= pb1) ? 1 : 0;
            if (t != cur_t) {
                cur_t = t;
                const unsigned short* wrow = Wt + ((size_t)(t * 3 + 0) * DIM + wcol) * DIM;
                #pragma unroll
                for (int kt = 0; kt < 4; ++kt) bfr[kt] = *(const bf16x8*)(wrow + kt * 32 + ko);
                bias = bq[t * DIM + wcol];
            }
            f32x4 acc = {0.f, 0.f, 0.f, 0.f};
            #pragma unroll
            for (int kt = 0; kt < 4; ++kt)
                acc = __builtin_amdgcn_mfma_f32_16x16x32_bf16(afrag[tt][kt], bfr[kt], acc, 0, 0, 0);
            #pragma unroll
            for (int r = 0; r < 4; ++r) {
                int lrow = (lane >> 4) * 4 + r;
                Qf[(size_t)(row0 + lrow) * DIM + wcol] = acc[r] + bias;
            }
        }
    }
    // KV phase: 2 column groups; K and V for the same column -> one packed dword
    #pragma unroll
    for (int g = 0; g < 2; ++g) {
        int wcol = g * 64 + col;
        int cur_t = -1;
        bf16x8 bK[4], bV[4];
        float bk_ = 0.f, bv_ = 0.f;
        #pragma unroll
        for (int tt = 0; tt < PCHUNK; ++tt) {
            if (!valid[tt]) continue;
            int row0 = row0s[tt];
            int t = (row0 >= pb3) ? 3 : (row0 >= pb2) ? 2 : (row0 >= pb1) ? 1 : 0;
            if (t != cur_t) {
                cur_t = t;
                const unsigned short* wrowK = Wt + ((size_t)(t * 3 + 1) * DIM + wcol) * DIM;
                const unsigned short* wrowV = Wt + ((size_t)(t * 3 + 2) * DIM + wcol) * DIM;
                #pragma unroll
                for (int kt = 0; kt < 4; ++kt) {
                    bK[kt] = *(const bf16x8*)(wrowK + kt * 32 + ko);
                    bV[kt] = *(const bf16x8*)(wrowV + kt * 32 + ko);
                }
                bk_ = bk[t * DIM + wcol];
                bv_ = bv[t * DIM + wcol];
            }
            f32x4 accK = {0.f, 0.f, 0.f, 0.f};
            f32x4 accV = {0.f, 0.f, 0.f, 0.f};
            #pragma unroll
            for (int kt = 0; kt < 4; ++kt) {
                accK = __builtin_amdgcn_mfma_f32_16x16x32_bf16(afrag[tt][kt], bK[kt], accK, 0, 0, 0);
                accV = __builtin_amdgcn_mfma_f32_16x16x32_bf16(afrag[tt][kt], bV[kt], accV, 0, 0, 0);
            }
            #pragma unroll
            for (int r = 0; r < 4; ++r) {
                int lrow = (lane >> 4) * 4 + r;
                unsigned d = (unsigned)f2bf(accK[r] + bk_) | ((unsigned)f2bf(accV[r] + bv_) << 16);
                KVu[(size_t)(row0 + lrow) * DIM + wcol] = d;
            }
        }
    }
}

// ============ E: fused attention + aggregation + skip + LN ============
// 256 threads = 4 waves; one wave per node. Each 32-lane HALF owns one edge;
// lane holds a 4-element quad. Score reduce = 2 width-4 shuffles.
__global__ __launch_bounds__(256) void k_attn(
    const float4* __restrict__ Qf4, const uint4* __restrict__ KV,
    const uint4* __restrict__ WCB,
    const float* __restrict__ x, const int* __restrict__ ntype,
    const int* __restrict__ slot,
    const int* __restrict__ offs, const int* __restrict__ bofs,
    const int2* __restrict__ edata,
    const float* __restrict__ rbias, const float* __restrict__ skip,
    const float* __restrict__ gmm, const float* __restrict__ bta,
    float* __restrict__ out)
{
    __shared__ float rb_s[NR * NH];
    if (threadIdx.x < NR * NH) rb_s[threadIdx.x] = rbias[threadIdx.x];
    __syncthreads();
    const int wave = threadIdx.x >> 6, lane = threadIdx.x & 63;
    const int n = blockIdx.x * 4 + wave;
    const int p = lane & 31;          // position quad index (elems 4p..4p+3)
    const int hi = lane >> 5;         // which edge of the pair this half owns
    const int h = p >> 2;             // head
    const int beg = offs[n] + bofs[n >> 10];
    const int end = offs[n + 1] + bofs[(n + 1) >> 10];

    const int sl = slot[n];           // own Q row in slot space (wave-uniform broadcast)
    const float4 q4 = Qf4[(size_t)sl * 32 + p];

    float Z = 0.f, a0 = 0.f, a1 = 0.f, a2 = 0.f, a3 = 0.f;

    // scores bounded; exp without max-shift is safe in f32 (softmax shift-invariant)
    // kv dword e = {k|v<<16}; wcb dword e = {wk|wv<<16}
    auto process = [&](int2 r) {
        int src = r.x & 0xffff;       // slot-space KV row
        unsigned cmb = ((unsigned)r.x) >> 16;
        uint4 kv = KV[(size_t)src * 32 + p];
        uint4 w = WCB[cmb * 32 + p];
        float pp = (q4.x * blo(w.x)) * blo(kv.x);
        pp = fmaf(q4.y * blo(w.y), blo(kv.y), pp);
        pp = fmaf(q4.z * blo(w.z), blo(kv.z), pp);
        pp = fmaf(q4.w * blo(w.w), blo(kv.w), pp);
        pp += __shfl_xor(pp, 1, 4);
        pp += __shfl_xor(pp, 2, 4);
        float ex = __expf(pp + rb_s[(cmb & 7) * NH + h] + __int_as_float(r.y));
        Z += ex;
        a0 = fmaf(bhi(kv.x) * bhi(w.x), ex, a0);
        a1 = fmaf(bhi(kv.y) * bhi(w.y), ex, a1);
        a2 = fmaf(bhi(kv.z) * bhi(w.z), ex, a2);
        a3 = fmaf(bhi(kv.w) * bhi(w.w), ex, a3);
    };

    int rem = end - beg;
    int j = beg;
    if (rem >= 4) {
        // 2-pair (4-edge) unroll with 1-iter-ahead edata prefetch
        int2 r0 = edata[j + hi];
        int2 r1 = edata[j + 2 + hi];
        while (true) {
            int2 c0 = r0, c1 = r1;
            j += 4; rem -= 4;
            if (rem >= 4) { r0 = edata[j + hi]; r1 = edata[j + 2 + hi]; }
            process(c0);
            process(c1);
            if (rem < 4) break;
        }
    }
    while (rem >= 2) {
        int2 c = edata[j + hi];
        process(c);
        j += 2; rem -= 2;
    }
    if (rem) {
        // single leftover edge: both halves compute it; gate the hi half to zero
        int2 r = edata[j];
        int src = r.x & 0xffff;
        unsigned cmb = ((unsigned)r.x) >> 16;
        uint4 kv = KV[(size_t)src * 32 + p];
        uint4 w = WCB[cmb * 32 + p];
        float pp = (q4.x * blo(w.x)) * blo(kv.x);
        pp = fmaf(q4.y * blo(w.y), blo(kv.y), pp);
        pp = fmaf(q4.z * blo(w.z), blo(kv.z), pp);
        pp = fmaf(q4.w * blo(w.w), blo(kv.w), pp);
        pp += __shfl_xor(pp, 1, 4);
        pp += __shfl_xor(pp, 2, 4);
        float ex = __expf(pp + rb_s[(cmb & 7) * NH + h] + __int_as_float(r.y));
        ex = hi ? 0.f : ex;
        Z += ex;
        a0 = fmaf(bhi(kv.x) * bhi(w.x), ex, a0);
        a1 = fmaf(bhi(kv.y) * bhi(w.y), ex, a1);
        a2 = fmaf(bhi(kv.z) * bhi(w.z), ex, a2);
        a3 = fmaf(bhi(kv.w) * bhi(w.w), ex, a3);
    }

    // merge the two halves (lanes l and l+32 hold the same positions)
    Z  += __shfl_xor(Z, 32, 64);
    a0 += __shfl_xor(a0, 32, 64);
    a1 += __shfl_xor(a1, 32, 64);
    a2 += __shfl_xor(a2, 32, 64);
    a3 += __shfl_xor(a3, 32, 64);

    float rz = 1.f / (Z + 1e-9f);
    int t = ntype[n];
    float alpha = 1.f / (1.f + __expf(-skip[t]));
    float4 x4 = ((const float4*)x)[(size_t)n * 32 + p];
    float m0 = fmaf(alpha, a0 * rz - x4.x, x4.x);
    float m1 = fmaf(alpha, a1 * rz - x4.y, x4.y);
    float m2 = fmaf(alpha, a2 * rz - x4.z, x4.z);
    float m3 = fmaf(alpha, a3 * rz - x4.w, x4.w);

    float s = (m0 + m1) + (m2 + m3);
    float s2 = fmaf(m0, m0, m1 * m1) + fmaf(m2, m2, m3 * m3);
    #pragma unroll
    for (int d = 32; d >= 1; d >>= 1) {
        s += __shfl_xor(s, d, 64);
        s2 += __shfl_xor(s2, d, 64);
    }
    // both halves duplicated -> divide by 2*DIM
    float mu = s * (1.f / (2 * DIM));
    float var = s2 * (1.f / (2 * DIM)) - mu * mu;
    float rstd = rsqrtf(var + 1e-5f);
    if (hi == 0) {
        float4 g4 = ((const float4*)gmm)[t * 32 + p];
        float4 b4 = ((const float4*)bta)[t * 32 + p];
        float4 o4;
        o4.x = (m0 - mu) * rstd * g4.x + b4.x;
        o4.y = (m1 - mu) * rstd * g4.y + b4.y;
        o4.z = (m2 - mu) * rstd * g4.z + b4.z;
        o4.w = (m3 - mu) * rstd * g4.w + b4.w;
        ((float4*)out)[(size_t)n * 32 + p] = o4;
    }
}

extern "C" void kernel_launch(void* const* d_in, const int* in_sizes, int n_in,
                              void* d_out, int out_size, void* d_ws, size_t ws_size,
                              hipStream_t stream) {
    const float* x      = (const float*)d_in[0];
    const int*   ntype  = (const int*)d_in[1];
    const int*   ei     = (const int*)d_in[2];
    const int*   etype  = (const int*)d_in[3];
    const int*   esign  = (const int*)d_in[4];
    const float* edist  = (const float*)d_in[5];
    const float* Wq     = (const float*)d_in[6];
    const float* bq     = (const float*)d_in[7];
    const float* Wk     = (const float*)d_in[8];
    const float* bk     = (const float*)d_in[9];
    const float* Wv     = (const float*)d_in[10];
    const float* bv     = (const float*)d_in[11];
    const float* rel_q  = (const float*)d_in[12];
    const float* rel_k  = (const float*)d_in[13];
    const float* rel_v  = (const float*)d_in[14];
    const float* skn    = (const float*)d_in[15];
    const float* svn    = (const float*)d_in[16];
    const float* rbias  = (const float*)d_in[17];
    const float* dalpha = (const float*)d_in[18];
    const float* dtau   = (const float*)d_in[19];
    const float* skip   = (const float*)d_in[20];
    const float* gmm    = (const float*)d_in[21];
    const float* bta    = (const float*)d_in[22];
    float* out = (float*)d_out;

    // All offsets are multiples of 512 B (row-aligned — KV/Q rows must not straddle
    // extra cache lines; the r10/r11 regression was a 160 B-misaligned KVu base).
    char* ws = (char*)d_ws;
    float*          Qf     = (float*)         (ws + 0);          // NPAD*512B (slot order)
    unsigned int*   KVu    = (unsigned int*)  (ws + 25632768);   // NPAD*512B (slot order, {k|v<<16})
    unsigned short* xb     = (unsigned short*)(ws + 51265536);   // 12.8 MB
    unsigned short* Wt     = (unsigned short*)(ws + 64065536);   // 393 KB
    uint4*          wcb    = (uint4*)         (ws + 64458752);   // 12.3 KB
    int*            cnt    = (int*)           (ws + 64471040);   // N
    int*            offs   = (int*)           (ws + 64672256);   // N+1
    int*            bsum   = (int*)           (ws + 64873472);   // 64
    int*            bofs   = (int*)           (ws + 64873984);   // 64
    int*            posw   = (int*)           (ws + 64874496);   // E = 3.2 MB
    int2*           edata  = (int2*)          (ws + 68074496);   // E*8 = 6.4 MB
    int*            opad   = (int*)           (ws + 74475008);   // NPAD_MAX
    int*            slot   = (int*)           (ws + 74675712);   // N
    int*            bhist  = (int*)           (ws + 74876416);   // 196*4
    int*            bbase  = (int*)           (ws + 74880512);   // 196*4
    int*            pb     = (int*)           (ws + 74884608);   // 5

    // 0. zero edge counters (must precede A's hist2 role)
    hipMemsetAsync(cnt, 0, (size_t)N_NODES * 4, stream);
    // A. typehist | prep | edge-histogram  (mutually independent)
    k_A <<<A_BLOCKS, 256, 0, stream>>>(ntype, bhist, opad,
                                       x, Wq, Wk, Wv, rel_q, rel_k, rel_v, skn, svn,
                                       xb, Wt, wcb, ei, cnt, posw);
    // B. typescan | scan1
    k_B <<<1 + NBLK2, 1024, 0, stream>>>(bhist, bbase, pb, cnt, offs, bsum);
    // C. scatter+slot | scan2
    k_C <<<NBLK_SCAN + 1, 256, 0, stream>>>(ntype, bbase, opad, slot, bsum, bofs, offs);
    // D1. emit (isolated for attribution; nontemporal scatter)
    k_emit <<<EMIT_BLOCKS, 256, 0, stream>>>(slot, ei, etype, esign, edist, dalpha, dtau,
                                             offs, bofs, posw, edata);
    // D2. projm (4 tiles/block, A-register-resident, 4x less Wt gather traffic)
    k_projm <<<PROJ_BLOCKS, 256, 0, stream>>>(xb, Wt, opad, pb, bq, bk, bv, Qf, KVu);
    // E. fused attention + aggregation + skip + LayerNorm
    k_attn <<<N_NODES / 4, 256, 0, stream>>>((const float4*)Qf, (const uint4*)KVu,
                                             (const uint4*)wcb, x, ntype, slot, offs, bofs,
                                             edata, rbias, skip, gmm, bta, out);
}

// Round 16
// 180.289 us; speedup vs baseline: 1.0232x; 1.0032x over previous
//
#include <hip/hip_runtime.h>

#define N_NODES 50000
#define N_EDGES 800000
#define DIM 128
#define NT 4
#define NR 6
#define NH 8
#define NBLK_SCAN ((N_NODES + 255) / 256)   // 196 (type-hist blocks)
#define NBLK2 ((N_NODES + 1023) / 1024)     // 49  (edge-count scan blocks)
#define NTILE_ROW 3129                      // ceil((N + 4*15)/16)
#define NPAD_MAX (NTILE_ROW * 16)           // 50064

#define WT_N   (NT * 3 * DIM * DIM)         // 196,608 elems
#define WCB_N  (24 * 32)                    // 768 uint4 entries
#define PREP_TOTAL (WT_N + WCB_N)           // 197,376 (xb staging eliminated r16)
#define PREP_BLOCKS ((PREP_TOTAL + 255) / 256)          // 772
#define HIST_BLOCKS (N_EDGES / 256)                     // 3125
#define A_PREP_BASE NBLK_SCAN
#define A_HIST_BASE (NBLK_SCAN + PREP_BLOCKS)
#define A_BLOCKS (A_HIST_BASE + HIST_BLOCKS)

#define PCHUNK 4
#define PROJ_BLOCKS ((NTILE_ROW + PCHUNK - 1) / PCHUNK)   // 783
#define EMIT_BLOCKS ((N_EDGES + 511) / 512)               // 1563 (2 edges/thread)

typedef __attribute__((ext_vector_type(8))) short bf16x8;
typedef __attribute__((ext_vector_type(4))) float f32x4;

__device__ __forceinline__ unsigned short f2bf(float f) {
    unsigned int u = __float_as_uint(f);
    return (unsigned short)((u + 0x7fffu + ((u >> 16) & 1u)) >> 16);
}
__device__ __forceinline__ float blo(unsigned int u) { return __uint_as_float(u << 16); }
__device__ __forceinline__ float bhi(unsigned int u) { return __uint_as_float(u & 0xffff0000u); }

__device__ __forceinline__ int sign_index(int s) {
    // es = where((s < -1)|(s==0), -2, clip(s,-1,1)); idx: -1->0, 1->1, else->2
    if (s < -1 || s == 0) return 2;
    return (s == -1) ? 0 : 1;
}

// ============ A: typehist | prep (Wt + wcb only) | hist2 ============
__global__ __launch_bounds__(256) void k_A(
    const int* __restrict__ ntype, int* __restrict__ bhist, int* __restrict__ opad,
    const float* __restrict__ Wq, const float* __restrict__ Wk, const float* __restrict__ Wv,
    const float* __restrict__ rel_q, const float* __restrict__ rel_k,
    const float* __restrict__ rel_v,
    const float* __restrict__ skn, const float* __restrict__ svn,
    unsigned short* __restrict__ Wt, uint4* __restrict__ wcb,
    const int* __restrict__ ei, int* __restrict__ cnt, int* __restrict__ posw)
{
    int blk = blockIdx.x;
    if (blk < NBLK_SCAN) {
        // ---- node-type histogram + opad init ----
        __shared__ int h[NT];
        if (threadIdx.x < NT) h[threadIdx.x] = 0;
        __syncthreads();
        int n = blk * 256 + threadIdx.x;
        if (n < N_NODES) atomicAdd(&h[ntype[n]], 1);
        if (n < NPAD_MAX) opad[n] = -1;
        __syncthreads();
        if (threadIdx.x < NT) bhist[blk * NT + threadIdx.x] = h[threadIdx.x];
        return;
    }
    if (blk < A_HIST_BASE) {
        // ---- prep: W->bf16 transposed | packed bf16 weight table ----
        int i = (blk - A_PREP_BASE) * 256 + threadIdx.x;
        if (i < WT_N) {
            int j = i;                     // Wt[ts][out][in], ts = t*3+sel
            int in = j & 127;
            int b2 = j >> 7;
            int out = b2 & 127;
            int ts = b2 >> 7;
            int sel = ts % 3, t = ts / 3;
            const float* W = sel == 0 ? Wq : (sel == 1 ? Wk : Wv);
            Wt[j] = f2bf(W[((size_t)t * DIM + in) * DIM + out]);
        } else if (i < PREP_TOTAL) {
            // wcb[cmb][p]: dword q = {wk(4p+q) | wv(4p+q)<<16}  (matches KV {k|v<<16})
            int j = i - WT_N;              // cmb*32 + p
            int p = j & 31;
            int cmb = j >> 5;
            int et = cmb & 7, sidx = cmb >> 3;
            if (et < NR) {
                int h2 = p >> 2;
                unsigned d[4];
                #pragma unroll
                for (int q = 0; q < 4; ++q) {
                    int o = 4 * p + q;
                    int rb = (et * NH + h2) * 16 + (o & 15);
                    float sgk = sidx == 0 ? -1.f : (sidx == 1 ? 1.f : skn[o]);
                    float sgv = sidx == 0 ? -1.f : (sidx == 1 ? 1.f : svn[o]);
                    float wk = rel_q[rb] * rel_k[rb] * sgk * 0.25f;
                    float wv = rel_v[rb] * sgv;
                    d[q] = (unsigned)f2bf(wk) | ((unsigned)f2bf(wv) << 16);
                }
                uint4 u; u.x = d[0]; u.y = d[1]; u.z = d[2]; u.w = d[3];
                wcb[cmb * 32 + p] = u;
            }
        }
        return;
    }
    // ---- edge histogram with position-within return (cnt pre-zeroed by memset) ----
    int e = (blk - A_HIST_BASE) * 256 + threadIdx.x;
    if (e < N_EDGES) posw[e] = atomicAdd(&cnt[ei[N_EDGES + e]], 1);
}

// ============ B: typescan (block 0) | scan1 (blocks 1..NBLK2) ============
__global__ __launch_bounds__(1024) void k_B(
    const int* __restrict__ bhist, int* __restrict__ bbase, int* __restrict__ pb_g,
    const int* __restrict__ cnt, int* __restrict__ offs, int* __restrict__ bsum)
{
    int tid = threadIdx.x;
    if (blockIdx.x == 0) {
        // ---- scan block histograms (type-major) -> per-(block,type) bases, padded x16 ----
        __shared__ int s[1024];
        __shared__ int pb[NT + 1];
        int t = tid / NBLK_SCAN;
        int b = tid - t * NBLK_SCAN;
        int v = (tid < NT * NBLK_SCAN) ? bhist[b * NT + t] : 0;
        s[tid] = v;
        __syncthreads();
        for (int d = 1; d < 1024; d <<= 1) {
            int add = (tid >= d) ? s[tid - d] : 0;
            __syncthreads();
            s[tid] += add;
            __syncthreads();
        }
        if (tid == 0) {
            int acc = 0;
            for (int tt = 0; tt < NT; ++tt) {
                pb[tt] = acc;
                int tot = s[(tt + 1) * NBLK_SCAN - 1] - (tt ? s[tt * NBLK_SCAN - 1] : 0);
                acc += ((tot + 15) >> 4) << 4;
            }
            pb[NT] = acc;
        }
        __syncthreads();
        if (tid < NT * NBLK_SCAN) {
            int excl = s[tid] - v;
            int base_t = t ? s[t * NBLK_SCAN - 1] : 0;
            bbase[b * NT + t] = pb[t] + (excl - base_t);
        }
        if (tid <= NT) pb_g[tid] = pb[tid];
        return;
    }
    // ---- scan1: block-local exclusive scan of edge counts (1024 elems/block) ----
    int sb = blockIdx.x - 1;
    __shared__ int s[1024];
    int i = sb * 1024 + tid;
    int v = (i < N_NODES) ? cnt[i] : 0;
    s[tid] = v;
    __syncthreads();
    for (int d = 1; d < 1024; d <<= 1) {
        int add = (tid >= d) ? s[tid - d] : 0;
        __syncthreads();
        s[tid] += add;
        __syncthreads();
    }
    if (i < N_NODES) offs[i] = s[tid] - v;
    if (tid == 1023) bsum[sb] = s[1023];
}

// ============ C: scatter+slot (blocks 0..195) | scan2 (block 196) ============
__global__ __launch_bounds__(256) void k_C(
    const int* __restrict__ ntype, const int* __restrict__ bbase, int* __restrict__ order_pad,
    int* __restrict__ slot,
    const int* __restrict__ bsum, int* __restrict__ bofs, int* __restrict__ offs)
{
    int blk = blockIdx.x;
    if (blk < NBLK_SCAN) {
        __shared__ int cur[NT];
        if (threadIdx.x < NT) cur[threadIdx.x] = bbase[blk * NT + threadIdx.x];
        __syncthreads();
        int n = blk * 256 + threadIdx.x;
        if (n < N_NODES) {
            int t = ntype[n];
            int pos = atomicAdd(&cur[t], 1);   // LDS atomic
            order_pad[pos] = n;
            slot[n] = pos;
        }
        return;
    }
    // ---- scan2 over NBLK2 block sums; offs[N] pre-compensated for bofs ----
    __shared__ int s[256];
    int t = threadIdx.x;
    int v = (t < NBLK2) ? bsum[t] : 0;
    s[t] = v;
    __syncthreads();
    for (int d = 1; d < 256; d <<= 1) {
        int add = (t >= d) ? s[t - d] : 0;
        __syncthreads();
        s[t] += add;
        __syncthreads();
    }
    if (t < NBLK2) {
        int b = s[t] - v;
        bofs[t] = b;
        if (t == NBLK2 - 1) offs[N_NODES] = N_EDGES - b;  // so offs[N]+bofs[N>>10]==E
    }
}

// ============ EMIT: dst-sorted edge records, 2 edges/thread, nontemporal stores ============
__global__ __launch_bounds__(256) void k_emit(
    const int* __restrict__ slot,
    const int* __restrict__ ei, const int* __restrict__ etype,
    const int* __restrict__ esign, const float* __restrict__ edist,
    const float* __restrict__ dalpha, const float* __restrict__ dtau,
    const int* __restrict__ offs, const int* __restrict__ bofs,
    const int* __restrict__ posw, int2* __restrict__ edata)
{
    int e0 = blockIdx.x * 512 + threadIdx.x;
    if (e0 >= N_EDGES) return;
    int e1 = e0 + 256;
    bool v1 = (e1 < N_EDGES);
    int dst0 = ei[N_EDGES + e0];
    int src0 = ei[e0];
    int dst1 = v1 ? ei[N_EDGES + e1] : 0;
    int src1 = v1 ? ei[e1] : 0;
    int pw0 = posw[e0];
    int pw1 = v1 ? posw[e1] : 0;
    int sl0 = slot[src0];                      // random gather (chain 0)
    int sl1 = slot[src1];                      // random gather (chain 1)
    int of0 = offs[dst0] + bofs[dst0 >> 10];   // random gather (chain 0)
    int of1 = offs[dst1] + bofs[dst1 >> 10];   // random gather (chain 1)
    int cmb0 = sign_index(esign[e0]) * 8 + etype[e0];
    int cmb1 = v1 ? (sign_index(esign[e1]) * 8 + etype[e1]) : 0;
    float rtau = 1.f / (dtau[0] + 1e-9f);
    float da = dalpha[0];
    float phi0 = da * __expf(-edist[e0] * rtau);
    float phi1 = da * __expf(-(v1 ? edist[e1] : 0.f) * rtau);
    // nontemporal 8B stores: avoid L2 line-ownership churn from random cross-XCD writes
    long long p0 = ((long long)(unsigned)__float_as_int(phi0) << 32)
                 | (unsigned)(sl0 | (cmb0 << 16));
    __builtin_nontemporal_store(p0, (long long*)(edata + of0 + pw0));
    if (v1) {
        long long p1 = ((long long)(unsigned)__float_as_int(phi1) << 32)
                     | (unsigned)(sl1 | (cmb1 << 16));
        __builtin_nontemporal_store(p1, (long long*)(edata + of1 + pw1));
    }
}

// ============ PROJM: MFMA projection, 4 row-tiles/block, direct f32 x loads ============
// A-fragments converted f32->bf16 in-register (xb staging pass eliminated, r16).
// Qf/KVu rows in SLOT order (contiguous per tile -> coalesced dword stores).
// KVu row dword e = {k(e) | v(e)<<16}. B-fragments reloaded only on type change.
__global__ __launch_bounds__(256) void k_projm(
    const float* __restrict__ x, const unsigned short* __restrict__ Wt,
    const int* __restrict__ order_pad, const int* __restrict__ pb_g,
    const float* __restrict__ bq, const float* __restrict__ bk, const float* __restrict__ bv,
    float* __restrict__ Qf, unsigned int* __restrict__ KVu)
{
    const int chunk = blockIdx.x;
    const int wave = threadIdx.x >> 6, lane = threadIdx.x & 63;
    const int col = wave * 16 + (lane & 15);   // 0..63
    const int ko = (lane >> 4) * 8;
    const int tmax = pb_g[NT];
    const int pb1 = pb_g[1], pb2 = pb_g[2], pb3 = pb_g[3];

    bf16x8 afrag[PCHUNK][4];
    int row0s[PCHUNK];
    bool valid[PCHUNK];
    #pragma unroll
    for (int tt = 0; tt < PCHUNK; ++tt) {
        int tile = chunk * PCHUNK + tt;
        int row0 = tile * 16;
        row0s[tt] = row0;
        bool v = (tile < NTILE_ROW) && (row0 < tmax);
        valid[tt] = v;
        int arow = row0 + (lane & 15);
        int nidA = v ? order_pad[arow] : -1;
        const float* xrow = x + (size_t)(nidA < 0 ? 0 : nidA) * DIM;
        #pragma unroll
        for (int kt = 0; kt < 4; ++kt) {
            float4 a = *(const float4*)(xrow + kt * 32 + ko);
            float4 b = *(const float4*)(xrow + kt * 32 + ko + 4);
            bf16x8 f;
            f[0] = (short)f2bf(a.x); f[1] = (short)f2bf(a.y);
            f[2] = (short)f2bf(a.z); f[3] = (short)f2bf(a.w);
            f[4] = (short)f2bf(b.x); f[5] = (short)f2bf(b.y);
            f[6] = (short)f2bf(b.z); f[7] = (short)f2bf(b.w);
            afrag[tt][kt] = f;
        }
    }

    // Q phase: 2 column groups; B-frags reused across the 4 tiles (reload on type change)
    #pragma unroll
    for (int g = 0; g < 2; ++g) {
        int wcol = g * 64 + col;
        int cur_t = -1;
        bf16x8 bfr[4];
        float bias = 0.f;
        #pragma unroll
        for (int tt = 0; tt < PCHUNK; ++tt) {
            if (!valid[tt]) continue;
            int row0 = row0s[tt];
            int t = (row0 >= pb3) ? 3 : (row0 >= pb2) ? 2 : (row0 >= pb1) ? 1 : 0;
            if (t != cur_t) {
                cur_t = t;
                const unsigned short* wrow = Wt + ((size_t)(t * 3 + 0) * DIM + wcol) * DIM;
                #pragma unroll
                for (int kt = 0; kt < 4; ++kt) bfr[kt] = *(const bf16x8*)(wrow + kt * 32 + ko);
                bias = bq[t * DIM + wcol];
            }
            f32x4 acc = {0.f, 0.f, 0.f, 0.f};
            #pragma unroll
            for (int kt = 0; kt < 4; ++kt)
                acc = __builtin_amdgcn_mfma_f32_16x16x32_bf16(afrag[tt][kt], bfr[kt], acc, 0, 0, 0);
            #pragma unroll
            for (int r = 0; r < 4; ++r) {
                int lrow = (lane >> 4) * 4 + r;
                Qf[(size_t)(row0 + lrow) * DIM + wcol] = acc[r] + bias;
            }
        }
    }
    // KV phase: 2 column groups; K and V for the same column -> one packed dword
    #pragma unroll
    for (int g = 0; g < 2; ++g) {
        int wcol = g * 64 + col;
        int cur_t = -1;
        bf16x8 bK[4], bV[4];
        float bk_ = 0.f, bv_ = 0.f;
        #pragma unroll
        for (int tt = 0; tt < PCHUNK; ++tt) {
            if (!valid[tt]) continue;
            int row0 = row0s[tt];
            int t = (row0 >= pb3) ? 3 : (row0 >= pb2) ? 2 : (row0 >= pb1) ? 1 : 0;
            if (t != cur_t) {
                cur_t = t;
                const unsigned short* wrowK = Wt + ((size_t)(t * 3 + 1) * DIM + wcol) * DIM;
                const unsigned short* wrowV = Wt + ((size_t)(t * 3 + 2) * DIM + wcol) * DIM;
                #pragma unroll
                for (int kt = 0; kt < 4; ++kt) {
                    bK[kt] = *(const bf16x8*)(wrowK + kt * 32 + ko);
                    bV[kt] = *(const bf16x8*)(wrowV + kt * 32 + ko);
                }
                bk_ = bk[t * DIM + wcol];
                bv_ = bv[t * DIM + wcol];
            }
            f32x4 accK = {0.f, 0.f, 0.f, 0.f};
            f32x4 accV = {0.f, 0.f, 0.f, 0.f};
            #pragma unroll
            for (int kt = 0; kt < 4; ++kt) {
                accK = __builtin_amdgcn_mfma_f32_16x16x32_bf16(afrag[tt][kt], bK[kt], accK, 0, 0, 0);
                accV = __builtin_amdgcn_mfma_f32_16x16x32_bf16(afrag[tt][kt], bV[kt], accV, 0, 0, 0);
            }
            #pragma unroll
            for (int r = 0; r < 4; ++r) {
                int lrow = (lane >> 4) * 4 + r;
                unsigned d = (unsigned)f2bf(accK[r] + bk_) | ((unsigned)f2bf(accV[r] + bv_) << 16);
                KVu[(size_t)(row0 + lrow) * DIM + wcol] = d;
            }
        }
    }
}

// ============ E: fused attention + aggregation + skip + LN ============
// 256 threads = 4 waves; one wave per node. Each 32-lane HALF owns one edge;
// lane holds a 4-element quad. Score reduce = 2 width-4 shuffles.
__global__ __launch_bounds__(256) void k_attn(
    const float4* __restrict__ Qf4, const uint4* __restrict__ KV,
    const uint4* __restrict__ WCB,
    const float* __restrict__ x, const int* __restrict__ ntype,
    const int* __restrict__ slot,
    const int* __restrict__ offs, const int* __restrict__ bofs,
    const int2* __restrict__ edata,
    const float* __restrict__ rbias, const float* __restrict__ skip,
    const float* __restrict__ gmm, const float* __restrict__ bta,
    float* __restrict__ out)
{
    __shared__ float rb_s[NR * NH];
    if (threadIdx.x < NR * NH) rb_s[threadIdx.x] = rbias[threadIdx.x];
    __syncthreads();
    const int wave = threadIdx.x >> 6, lane = threadIdx.x & 63;
    const int n = blockIdx.x * 4 + wave;
    const int p = lane & 31;          // position quad index (elems 4p..4p+3)
    const int hi = lane >> 5;         // which edge of the pair this half owns
    const int h = p >> 2;             // head
    const int beg = offs[n] + bofs[n >> 10];
    const int end = offs[n + 1] + bofs[(n + 1) >> 10];

    const int sl = slot[n];           // own Q row in slot space (wave-uniform broadcast)
    const float4 q4 = Qf4[(size_t)sl * 32 + p];

    float Z = 0.f, a0 = 0.f, a1 = 0.f, a2 = 0.f, a3 = 0.f;

    // scores bounded; exp without max-shift is safe in f32 (softmax shift-invariant)
    // kv dword e = {k|v<<16}; wcb dword e = {wk|wv<<16}
    auto process = [&](int2 r) {
        int src = r.x & 0xffff;       // slot-space KV row
        unsigned cmb = ((unsigned)r.x) >> 16;
        uint4 kv = KV[(size_t)src * 32 + p];
        uint4 w = WCB[cmb * 32 + p];
        float pp = (q4.x * blo(w.x)) * blo(kv.x);
        pp = fmaf(q4.y * blo(w.y), blo(kv.y), pp);
        pp = fmaf(q4.z * blo(w.z), blo(kv.z), pp);
        pp = fmaf(q4.w * blo(w.w), blo(kv.w), pp);
        pp += __shfl_xor(pp, 1, 4);
        pp += __shfl_xor(pp, 2, 4);
        float ex = __expf(pp + rb_s[(cmb & 7) * NH + h] + __int_as_float(r.y));
        Z += ex;
        a0 = fmaf(bhi(kv.x) * bhi(w.x), ex, a0);
        a1 = fmaf(bhi(kv.y) * bhi(w.y), ex, a1);
        a2 = fmaf(bhi(kv.z) * bhi(w.z), ex, a2);
        a3 = fmaf(bhi(kv.w) * bhi(w.w), ex, a3);
    };

    int rem = end - beg;
    int j = beg;
    if (rem >= 4) {
        // 2-pair (4-edge) unroll with 1-iter-ahead edata prefetch
        int2 r0 = edata[j + hi];
        int2 r1 = edata[j + 2 + hi];
        while (true) {
            int2 c0 = r0, c1 = r1;
            j += 4; rem -= 4;
            if (rem >= 4) { r0 = edata[j + hi]; r1 = edata[j + 2 + hi]; }
            process(c0);
            process(c1);
            if (rem < 4) break;
        }
    }
    while (rem >= 2) {
        int2 c = edata[j + hi];
        process(c);
        j += 2; rem -= 2;
    }
    if (rem) {
        // single leftover edge: both halves compute it; gate the hi half to zero
        int2 r = edata[j];
        int src = r.x & 0xffff;
        unsigned cmb = ((unsigned)r.x) >> 16;
        uint4 kv = KV[(size_t)src * 32 + p];
        uint4 w = WCB[cmb * 32 + p];
        float pp = (q4.x * blo(w.x)) * blo(kv.x);
        pp = fmaf(q4.y * blo(w.y), blo(kv.y), pp);
        pp = fmaf(q4.z * blo(w.z), blo(kv.z), pp);
        pp = fmaf(q4.w * blo(w.w), blo(kv.w), pp);
        pp += __shfl_xor(pp, 1, 4);
        pp += __shfl_xor(pp, 2, 4);
        float ex = __expf(pp + rb_s[(cmb & 7) * NH + h] + __int_as_float(r.y));
        ex = hi ? 0.f : ex;
        Z += ex;
        a0 = fmaf(bhi(kv.x) * bhi(w.x), ex, a0);
        a1 = fmaf(bhi(kv.y) * bhi(w.y), ex, a1);
        a2 = fmaf(bhi(kv.z) * bhi(w.z), ex, a2);
        a3 = fmaf(bhi(kv.w) * bhi(w.w), ex, a3);
    }

    // merge the two halves (lanes l and l+32 hold the same positions)
    Z  += __shfl_xor(Z, 32, 64);
    a0 += __shfl_xor(a0, 32, 64);
    a1 += __shfl_xor(a1, 32, 64);
    a2 += __shfl_xor(a2, 32, 64);
    a3 += __shfl_xor(a3, 32, 64);

    float rz = 1.f / (Z + 1e-9f);
    int t = ntype[n];
    float alpha = 1.f / (1.f + __expf(-skip[t]));
    float4 x4 = ((const float4*)x)[(size_t)n * 32 + p];
    float m0 = fmaf(alpha, a0 * rz - x4.x, x4.x);
    float m1 = fmaf(alpha, a1 * rz - x4.y, x4.y);
    float m2 = fmaf(alpha, a2 * rz - x4.z, x4.z);
    float m3 = fmaf(alpha, a3 * rz - x4.w, x4.w);

    float s = (m0 + m1) + (m2 + m3);
    float s2 = fmaf(m0, m0, m1 * m1) + fmaf(m2, m2, m3 * m3);
    #pragma unroll
    for (int d = 32; d >= 1; d >>= 1) {
        s += __shfl_xor(s, d, 64);
        s2 += __shfl_xor(s2, d, 64);
    }
    // both halves duplicated -> divide by 2*DIM
    float mu = s * (1.f / (2 * DIM));
    float var = s2 * (1.f / (2 * DIM)) - mu * mu;
    float rstd = rsqrtf(var + 1e-5f);
    if (hi == 0) {
        float4 g4 = ((const float4*)gmm)[t * 32 + p];
        float4 b4 = ((const float4*)bta)[t * 32 + p];
        float4 o4;
        o4.x = (m0 - mu) * rstd * g4.x + b4.x;
        o4.y = (m1 - mu) * rstd * g4.y + b4.y;
        o4.z = (m2 - mu) * rstd * g4.z + b4.z;
        o4.w = (m3 - mu) * rstd * g4.w + b4.w;
        ((float4*)out)[(size_t)n * 32 + p] = o4;
    }
}

extern "C" void kernel_launch(void* const* d_in, const int* in_sizes, int n_in,
                              void* d_out, int out_size, void* d_ws, size_t ws_size,
                              hipStream_t stream) {
    const float* x      = (const float*)d_in[0];
    const int*   ntype  = (const int*)d_in[1];
    const int*   ei     = (const int*)d_in[2];
    const int*   etype  = (const int*)d_in[3];
    const int*   esign  = (const int*)d_in[4];
    const float* edist  = (const float*)d_in[5];
    const float* Wq     = (const float*)d_in[6];
    const float* bq     = (const float*)d_in[7];
    const float* Wk     = (const float*)d_in[8];
    const float* bk     = (const float*)d_in[9];
    const float* Wv     = (const float*)d_in[10];
    const float* bv     = (const float*)d_in[11];
    const float* rel_q  = (const float*)d_in[12];
    const float* rel_k  = (const float*)d_in[13];
    const float* rel_v  = (const float*)d_in[14];
    const float* skn    = (const float*)d_in[15];
    const float* svn    = (const float*)d_in[16];
    const float* rbias  = (const float*)d_in[17];
    const float* dalpha = (const float*)d_in[18];
    const float* dtau   = (const float*)d_in[19];
    const float* skip   = (const float*)d_in[20];
    const float* gmm    = (const float*)d_in[21];
    const float* bta    = (const float*)d_in[22];
    float* out = (float*)d_out;

    // All offsets are multiples of 512 B (row-aligned — KV/Q rows must not straddle
    // extra cache lines; the r10/r11 regression was a 160 B-misaligned KVu base).
    char* ws = (char*)d_ws;
    float*          Qf     = (float*)         (ws + 0);          // NPAD*512B (slot order)
    unsigned int*   KVu    = (unsigned int*)  (ws + 25632768);   // NPAD*512B (slot order, {k|v<<16})
    unsigned short* Wt     = (unsigned short*)(ws + 51265536);   // 393 KB
    uint4*          wcb    = (uint4*)         (ws + 51658752);   // 12.3 KB
    int*            cnt    = (int*)           (ws + 51671040);   // N
    int*            offs   = (int*)           (ws + 51872256);   // N+1
    int*            bsum   = (int*)           (ws + 52073472);   // 64
    int*            bofs   = (int*)           (ws + 52073984);   // 64
    int*            posw   = (int*)           (ws + 52074496);   // E = 3.2 MB
    int2*           edata  = (int2*)          (ws + 55274496);   // E*8 = 6.4 MB
    int*            opad   = (int*)           (ws + 61675008);   // NPAD_MAX
    int*            slot   = (int*)           (ws + 61875712);   // N
    int*            bhist  = (int*)           (ws + 62076416);   // 196*4
    int*            bbase  = (int*)           (ws + 62080512);   // 196*4
    int*            pb     = (int*)           (ws + 62084608);   // 5

    // 0. zero edge counters (must precede A's hist2 role)
    hipMemsetAsync(cnt, 0, (size_t)N_NODES * 4, stream);
    // A. typehist | prep (Wt+wcb only; xb staging eliminated) | edge-histogram
    k_A <<<A_BLOCKS, 256, 0, stream>>>(ntype, bhist, opad,
                                       Wq, Wk, Wv, rel_q, rel_k, rel_v, skn, svn,
                                       Wt, wcb, ei, cnt, posw);
    // B. typescan | scan1
    k_B <<<1 + NBLK2, 1024, 0, stream>>>(bhist, bbase, pb, cnt, offs, bsum);
    // C. scatter+slot | scan2
    k_C <<<NBLK_SCAN + 1, 256, 0, stream>>>(ntype, bbase, opad, slot, bsum, bofs, offs);
    // D1. emit (nontemporal scatter)
    k_emit <<<EMIT_BLOCKS, 256, 0, stream>>>(slot, ei, etype, esign, edist, dalpha, dtau,
                                             offs, bofs, posw, edata);
    // D2. projm (direct f32 x loads, in-register bf16 conversion)
    k_projm <<<PROJ_BLOCKS, 256, 0, stream>>>(x, Wt, opad, pb, bq, bk, bv, Qf, KVu);
    // E. fused attention + aggregation + skip + LayerNorm
    k_attn <<<N_NODES / 4, 256, 0, stream>>>((const float4*)Qf, (const uint4*)KVu,
                                             (const uint4*)wcb, x, ntype, slot, offs, bofs,
                                             edata, rbias, skip, gmm, bta, out);
}